// Round 8
// baseline (1017.284 us; speedup 1.0000x reference)
//
#include <hip/hip_runtime.h>

// Problem dims
constexpr int Bb  = 64;      // batch
constexpr int Tt  = 1024;    // time
constexpr int Dd  = 288;     // padded input feature dim
constexpr int Ss  = 256;     // STATE_DIM
constexpr int ALa = 16;      // ACT_LEN
constexpr int Ll  = 256;     // LATENT
constexpr int Ee  = 512;     // ENC
constexpr int CC  = 8;       // scan chunk length
constexpr int NCh = 128;     // number of chunks (CC*NCh == Tt)
constexpr int NSC = 16;      // superchunks for boundary recurrence
constexpr int SC  = 8;       // chunk-boundaries per superchunk
constexpr int DEC_CHUNKS = 8;
constexpr int DEC_ROWS = (Bb*Tt)/DEC_CHUNKS;  // 8192 rows per chunk

#define LKY(v) ((v) >= 0.f ? (v) : 0.01f*(v))

using f32x4  = __attribute__((ext_vector_type(4))) float;
using short8 = __attribute__((ext_vector_type(8))) short;
typedef unsigned short ushort_t;

__device__ __forceinline__ unsigned short f2bf(float f){
  unsigned int u = __float_as_uint(f);
  u = (u + 0x7fffu + ((u >> 16) & 1u)) >> 16;   // RNE
  return (unsigned short)u;
}
__device__ __forceinline__ float bf2f(unsigned short h){
  return __uint_as_float(((unsigned int)h) << 16);
}

// Async global->LDS 16B copy. LDS dest must be wave-uniform-base + lane*16
// (all call sites below satisfy this: per-wave q is constant, lane index is
// contiguous). Bytes land after the vmcnt(0) drain at __syncthreads().
__device__ __forceinline__ void gld16(void* lds, const void* g){
  __builtin_amdgcn_global_load_lds(
      (__attribute__((address_space(1))) void*)g,
      (__attribute__((address_space(3))) void*)lds, 16, 0, 0);
}

// ---------------------------------------------------------------------------
// Encoder dense layer, split-K: grid (row, N/32); 256 thr = 32 cols x 8 kslc.
// (1024 blocks of split-K beat 64 fat blocks by ~130 us.)
// ---------------------------------------------------------------------------
__global__ __launch_bounds__(256) void enc_dense(
    const float* __restrict__ xin, int xstride,
    const float* __restrict__ W, const float* __restrict__ bias,
    float* __restrict__ out, int K, int N, int act)
{
  int b = blockIdx.x, col0 = blockIdx.y * 32;
  int tid = threadIdx.x;
  int tx = tid & 31, tk = tid >> 5;
  __shared__ float x[512];
  __shared__ float part[8][33];
  for (int k = tid; k < K; k += 256) x[k] = xin[(long)b*xstride + k];
  __syncthreads();
  int j = col0 + tx;
  float p0=0.f,p1=0.f,p2=0.f,p3=0.f;
  int iters = K >> 3;
  #pragma unroll 2
  for (int i = 0; i < iters; i += 4){
    int k0 = tk + 8*i;
    p0 = fmaf(x[k0     ], W[(long)(k0     )*N + j], p0);
    p1 = fmaf(x[k0 +  8], W[(long)(k0 +  8)*N + j], p1);
    p2 = fmaf(x[k0 + 16], W[(long)(k0 + 16)*N + j], p2);
    p3 = fmaf(x[k0 + 24], W[(long)(k0 + 24)*N + j], p3);
  }
  part[tk][tx] = (p0+p1)+(p2+p3);
  __syncthreads();
  if (tid < 32){
    float s = part[0][tid];
    #pragma unroll
    for (int q = 1; q < 8; ++q) s += part[q][tid];
    s += bias[col0 + tid];
    out[b*N + col0 + tid] = act ? LKY(s) : s;
  }
}

// ---------------------------------------------------------------------------
// Batched 256x256 matmul C = X @ Y (up to 4 jobs per launch, blockIdx.y=job).
// Optional fp32 out + split planes ((k>>3)*256+n)*8+(k&7).
// ---------------------------------------------------------------------------
struct MMJob { const float* X; const float* Y; float* Cf; ushort_t* Ch; ushort_t* Cl; };
struct MMJobs { MMJob j[4]; };

__global__ __launch_bounds__(256) void matmul_gb(MMJobs jobs)
{
  MMJob jb = jobs.j[blockIdx.y];
  int i = blockIdx.x;
  int tid = threadIdx.x;
  int jg = tid & 63, tk = tid >> 6;
  __shared__ float row[256];
  __shared__ float4 part[4][64];
  if (tid < 256) row[tid] = jb.X[i*256 + tid];
  __syncthreads();
  int j4 = jg*4;
  float4 p0 = make_float4(0,0,0,0), p1 = make_float4(0,0,0,0);
  int kb = tk*64;
  #pragma unroll 4
  for (int k = kb; k < kb+64; k += 2){
    float x0 = row[k], x1 = row[k+1];
    float4 y0 = *(const float4*)&jb.Y[(k  )*256 + j4];
    float4 y1 = *(const float4*)&jb.Y[(k+1)*256 + j4];
    p0.x = fmaf(x0,y0.x,p0.x); p0.y = fmaf(x0,y0.y,p0.y);
    p0.z = fmaf(x0,y0.z,p0.z); p0.w = fmaf(x0,y0.w,p0.w);
    p1.x = fmaf(x1,y1.x,p1.x); p1.y = fmaf(x1,y1.y,p1.y);
    p1.z = fmaf(x1,y1.z,p1.z); p1.w = fmaf(x1,y1.w,p1.w);
  }
  p0.x+=p1.x; p0.y+=p1.y; p0.z+=p1.z; p0.w+=p1.w;
  part[tk][jg] = p0;
  __syncthreads();
  if (tid < 64){
    float4 s = part[0][tid];
    #pragma unroll
    for (int q = 1; q < 4; ++q){
      float4 v = part[q][tid];
      s.x+=v.x; s.y+=v.y; s.z+=v.z; s.w+=v.w;
    }
    int j = tid*4;
    if (jb.Cf) *(float4*)&jb.Cf[i*256 + j] = s;
    if (jb.Ch){
      float vv[4] = {s.x,s.y,s.z,s.w};
      #pragma unroll
      for (int e = 0; e < 4; ++e){
        ushort_t h = f2bf(vv[e]);
        int o = ((i>>3)*256 + j + e)*8 + (i&7);
        jb.Ch[o] = h; jb.Cl[o] = f2bf(vv[e] - bf2f(h));
      }
    }
  }
}

// ---------------------------------------------------------------------------
// Fused plane prep: A^1 plane (65536 elems) + B_w^T padded plane (8192 elems).
// ---------------------------------------------------------------------------
__global__ __launch_bounds__(256) void prep_a1bw(
    const float* __restrict__ A, const float* __restrict__ B,
    ushort_t* __restrict__ AH, ushort_t* __restrict__ AL,
    ushort_t* __restrict__ Bh, ushort_t* __restrict__ Bl)
{
  int o = blockIdx.x*256 + threadIdx.x;
  if (o < 65536){
    int j = o & 7, rest = o >> 3;
    int n = rest & 255, t8 = rest >> 8;
    int k = t8*8 + j;
    float v = A[k*256 + n];
    ushort_t h = f2bf(v);
    AH[o] = h; AL[o] = f2bf(v - bf2f(h));
  } else {
    int ob = o - 65536;                      // 0..8191
    int j = ob & 7, rest = ob >> 3;
    int n = rest & 255, kq = rest >> 8;
    int k = kq*8 + j;
    float v = (k < ALa) ? B[k*256 + n] : 0.f;
    ushort_t h = f2bf(v);
    Bh[ob] = h; Bl[ob] = f2bf(v - bf2f(h));
  }
}

// ---------------------------------------------------------------------------
// Fused decoder weight-plane prep (w1: 131072, w2: 262144, w3: 131072 elems).
// ---------------------------------------------------------------------------
__global__ __launch_bounds__(256) void prep_dec(
    const float* __restrict__ w1, const float* __restrict__ w2,
    const float* __restrict__ w3, ushort_t* __restrict__ Wh,
    ushort_t* __restrict__ Wl)
{
  long o = (long)blockIdx.x*256 + threadIdx.x;   // 0..524287
  const float* W; ushort_t* H; ushort_t* L; int N; long oo;
  if (o < 131072){ W = w1; H = Wh;          L = Wl;          N = 512; oo = o; }
  else if (o < 393216){ W = w2; H = Wh + 131072; L = Wl + 131072; N = 512; oo = o - 131072; }
  else { W = w3; H = Wh + 393216; L = Wl + 393216; N = 256; oo = o - 393216; }
  int j = (int)(oo & 7);
  long rest = oo >> 3;
  int n = (int)(rest % N);
  int t8 = (int)(rest / N);
  int k = t8*8 + j;
  float v = W[(long)k*N + n];
  ushort_t h = f2bf(v);
  H[oo] = h; L[oo] = f2bf(v - bf2f(h));
}

// ---------------------------------------------------------------------------
// MFMA chunk scan (zero-init pass), N-SPLIT: grid (chunk, nb); each block owns
// 32 batch columns of one chunk. wend/zout layouts unchanged.
// ---------------------------------------------------------------------------
__device__ __forceinline__ void load_afrag(
    const ushort_t* __restrict__ P, int kq, int m0, short8* dst)
{
  #pragma unroll
  for (int mt = 0; mt < 4; ++mt)
    dst[mt] = *(const short8*)&P[((long)kq*256 + m0 + mt*16)*8];
}

__global__ __launch_bounds__(256) void scan_mfma(
    const float* __restrict__ in0,
    const ushort_t* __restrict__ AtH, const ushort_t* __restrict__ AtL,
    const ushort_t* __restrict__ BtH, const ushort_t* __restrict__ BtL,
    float* __restrict__ wend, float* __restrict__ zout)
{
  int chunk = blockIdx.x;
  int n0 = blockIdx.y * 32;            // batch-column half
  int tid = threadIdx.x;
  int wave = tid >> 6, lane = tid & 63;
  int quad = lane >> 4, l16 = lane & 15;
  int mwave = wave * 64;
  int m0 = mwave + l16;

  __shared__ ushort_t StH[8192];
  __shared__ ushort_t StL[8192];

  short8 Bfh[4], Bfl[4];
  #pragma unroll
  for (int mt = 0; mt < 4; ++mt){
    int off = ((quad)*256 + m0 + mt*16)*8;
    Bfh[mt] = *(const short8*)&BtH[off];
    Bfl[mt] = *(const short8*)&BtL[off];
  }

  f32x4 acc[4][2];
  #pragma unroll
  for (int mt = 0; mt < 4; ++mt)
    #pragma unroll
    for (int nt = 0; nt < 2; ++nt) acc[mt][nt] = (f32x4){0.f,0.f,0.f,0.f};

  const float* ubase[2];
  #pragma unroll
  for (int nt = 0; nt < 2; ++nt)
    ubase[nt] = in0 + (long)(n0 + nt*16 + l16)*(Tt*Dd) + (Ss + ALa) + quad*8;

  short8 Ahb[2][4], Alb[2][4];

  for (int tt = 0; tt < CC; ++tt){
    int t = chunk*CC + tt;
    float4 uq[2][2];
    #pragma unroll
    for (int nt = 0; nt < 2; ++nt){
      if (quad < 2){
        const float* up = ubase[nt] + (long)t*Dd;
        uq[nt][0] = *(const float4*)up;
        uq[nt][1] = *(const float4*)(up + 4);
      } else {
        uq[nt][0] = make_float4(0,0,0,0); uq[nt][1] = make_float4(0,0,0,0);
      }
    }

    if (tt > 0){
      load_afrag(AtH, 0*4 + quad, m0, Ahb[0]);
      load_afrag(AtL, 0*4 + quad, m0, Alb[0]);
      #pragma unroll
      for (int kt = 0; kt < 8; ++kt){
        int cur = kt & 1;
        if (kt < 7){
          load_afrag(AtH, (kt+1)*4 + quad, m0, Ahb[cur^1]);
          load_afrag(AtL, (kt+1)*4 + quad, m0, Alb[cur^1]);
        }
        short8 Sbh[2], Sbl[2];
        #pragma unroll
        for (int nt = 0; nt < 2; ++nt){
          int off = ((kt*4 + quad)*32 + nt*16 + l16)*8;
          Sbh[nt] = *(const short8*)&StH[off];
          Sbl[nt] = *(const short8*)&StL[off];
        }
        #pragma unroll
        for (int mt = 0; mt < 4; ++mt)
          #pragma unroll
          for (int nt = 0; nt < 2; ++nt){
            acc[mt][nt] = __builtin_amdgcn_mfma_f32_16x16x32_bf16(Ahb[cur][mt], Sbh[nt], acc[mt][nt], 0,0,0);
            acc[mt][nt] = __builtin_amdgcn_mfma_f32_16x16x32_bf16(Ahb[cur][mt], Sbl[nt], acc[mt][nt], 0,0,0);
            acc[mt][nt] = __builtin_amdgcn_mfma_f32_16x16x32_bf16(Alb[cur][mt], Sbh[nt], acc[mt][nt], 0,0,0);
          }
      }
    }

    short8 uh[2], ul[2];
    #pragma unroll
    for (int nt = 0; nt < 2; ++nt){
      float v[8] = {uq[nt][0].x,uq[nt][0].y,uq[nt][0].z,uq[nt][0].w,
                    uq[nt][1].x,uq[nt][1].y,uq[nt][1].z,uq[nt][1].w};
      ushort_t hs[8], ls[8];
      #pragma unroll
      for (int j = 0; j < 8; ++j){
        hs[j] = f2bf(v[j]);
        ls[j] = f2bf(v[j] - bf2f(hs[j]));
      }
      uh[nt] = *(const short8*)hs; ul[nt] = *(const short8*)ls;
    }
    #pragma unroll
    for (int mt = 0; mt < 4; ++mt)
      #pragma unroll
      for (int nt = 0; nt < 2; ++nt){
        acc[mt][nt] = __builtin_amdgcn_mfma_f32_16x16x32_bf16(Bfh[mt], uh[nt], acc[mt][nt], 0,0,0);
        acc[mt][nt] = __builtin_amdgcn_mfma_f32_16x16x32_bf16(Bfh[mt], ul[nt], acc[mt][nt], 0,0,0);
        acc[mt][nt] = __builtin_amdgcn_mfma_f32_16x16x32_bf16(Bfl[mt], uh[nt], acc[mt][nt], 0,0,0);
      }

    __syncthreads();

    #pragma unroll
    for (int mt = 0; mt < 4; ++mt){
      int mb = mwave + mt*16 + quad*4;
      #pragma unroll
      for (int nt = 0; nt < 2; ++nt){
        int n = nt*16 + l16;
        int gn = n0 + n;
        f32x4 v = acc[mt][nt];
        *(float4*)&zout[((long)gn*Tt + t)*Ll + mb] = make_float4(v[0],v[1],v[2],v[3]);
        if (tt == CC-1)
          *(float4*)&wend[((long)chunk*Bb + gn)*Ll + mb] = make_float4(v[0],v[1],v[2],v[3]);
        #pragma unroll
        for (int reg = 0; reg < 4; ++reg){
          int m = mb + reg;
          ushort_t h = f2bf(v[reg]);
          ushort_t l = f2bf(v[reg] - bf2f(h));
          int so = ((m>>3)*32 + n)*8 + (m&7);
          StH[so] = h; StL[so] = l;
        }
        acc[mt][nt] = (f32x4){0.f,0.f,0.f,0.f};
      }
    }
    __syncthreads();
  }
}

// ---------------------------------------------------------------------------
// pass2 (Kogge-Stone MFMA): boundary recurrence via parallel prefix-doubling.
// ---------------------------------------------------------------------------
__device__ __forceinline__ void frag_init_state512(
    const float* __restrict__ src, ushort_t* StH, ushort_t* StL, int tid)
{
  #pragma unroll
  for (int it = 0; it < 4; ++it){
    int idx = tid + it*512;        // 0..2047
    int m8 = idx >> 6, n = idx & 63;
    const float* p = src + (long)n*256 + m8*8;
    float4 v0 = *(const float4*)p;
    float4 v1 = *(const float4*)(p + 4);
    float vv[8] = {v0.x,v0.y,v0.z,v0.w,v1.x,v1.y,v1.z,v1.w};
    ushort_t hs[8], ls[8];
    #pragma unroll
    for (int j = 0; j < 8; ++j){
      hs[j] = f2bf(vv[j]);
      ls[j] = f2bf(vv[j] - bf2f(hs[j]));
    }
    *(uint4*)&StH[(m8*64 + n)*8] = *(const uint4*)hs;
    *(uint4*)&StL[(m8*64 + n)*8] = *(const uint4*)ls;
  }
}

__device__ __forceinline__ void p2_load_A(
    const ushort_t* __restrict__ PH, const ushort_t* __restrict__ PL,
    int wave, int lane, short8 Ah[2][8], short8 Al[2][8])
{
  int quad = lane >> 4, l16 = lane & 15;
  int m0 = wave*32 + l16;
  #pragma unroll
  for (int kt = 0; kt < 8; ++kt){
    int kq = kt*4 + quad;
    #pragma unroll
    for (int mt = 0; mt < 2; ++mt){
      Ah[mt][kt] = *(const short8*)&PH[((long)kq*256 + m0 + mt*16)*8];
      Al[mt][kt] = *(const short8*)&PL[((long)kq*256 + m0 + mt*16)*8];
    }
  }
}

// out = accsrc + bsrc @ P  (single barrier; no LDS writeback)
__device__ __forceinline__ void ks_gemm_body(
    const ushort_t* __restrict__ PH, const ushort_t* __restrict__ PL,
    const float* __restrict__ accsrc, const float* __restrict__ bsrc,
    float* __restrict__ outp, ushort_t* StH, ushort_t* StL)
{
  int tid = threadIdx.x;
  int wave = tid >> 6, lane = tid & 63;
  int quad = lane >> 4, l16 = lane & 15;
  int mwave = wave*32;

  short8 Ah[2][8], Al[2][8];
  p2_load_A(PH, PL, wave, lane, Ah, Al);
  frag_init_state512(bsrc, StH, StL, tid);

  f32x4 acc[2][4];
  #pragma unroll
  for (int mt = 0; mt < 2; ++mt){
    int mb = mwave + mt*16 + quad*4;
    #pragma unroll
    for (int nt = 0; nt < 4; ++nt){
      int n = nt*16 + l16;
      float4 v = *(const float4*)&accsrc[(long)n*256 + mb];
      acc[mt][nt] = (f32x4){v.x, v.y, v.z, v.w};
    }
  }
  __syncthreads();

  #pragma unroll
  for (int kt = 0; kt < 8; ++kt){
    #pragma unroll
    for (int nt = 0; nt < 4; ++nt){
      int off = ((kt*4 + quad)*64 + nt*16 + l16)*8;
      short8 Sbh = *(const short8*)&StH[off];
      short8 Sbl = *(const short8*)&StL[off];
      #pragma unroll
      for (int mt = 0; mt < 2; ++mt){
        acc[mt][nt] = __builtin_amdgcn_mfma_f32_16x16x32_bf16(Ah[mt][kt], Sbh, acc[mt][nt], 0,0,0);
        acc[mt][nt] = __builtin_amdgcn_mfma_f32_16x16x32_bf16(Ah[mt][kt], Sbl, acc[mt][nt], 0,0,0);
        acc[mt][nt] = __builtin_amdgcn_mfma_f32_16x16x32_bf16(Al[mt][kt], Sbh, acc[mt][nt], 0,0,0);
      }
    }
  }

  #pragma unroll
  for (int mt = 0; mt < 2; ++mt){
    int mb = mwave + mt*16 + quad*4;
    #pragma unroll
    for (int nt = 0; nt < 4; ++nt){
      int n = nt*16 + l16;
      f32x4 v = acc[mt][nt];
      *(float4*)&outp[(long)n*256 + mb] = make_float4(v[0],v[1],v[2],v[3]);
    }
  }
}

// Source resolver for KS-global round 1 (virtual init sequence):
//   x[0] = z0, x[c] = LS[8c-1] (superchunk-local full prefix end).
__device__ __forceinline__ const float* ks_src(
    const float* __restrict__ in, const float* __restrict__ z0,
    const float* __restrict__ pbend, int c, int init_mode)
{
  if (!init_mode) return in + (long)c*(Bb*Ll);
  return (c == 0) ? z0 : (pbend + (long)(8*c - 1)*(Bb*Ll));
}

// One Kogge-Stone round: out[c] = in[c] + in[c-d] @ P  (or copy if below d
// within its segment). local_seg=1: 8-chunk segments; else global sequence.
__global__ __launch_bounds__(512) void ks_round(
    const ushort_t* __restrict__ PH, const ushort_t* __restrict__ PL,
    const float* __restrict__ in, const float* __restrict__ z0,
    const float* __restrict__ pbend,
    float* __restrict__ out, long outStride, int d, int local_seg, int init_mode)
{
  int c = blockIdx.x;
  int tid = threadIdx.x;
  int pos = local_seg ? (c & 7) : c;
  const float* src_c = ks_src(in, z0, pbend, c, init_mode);
  float* op = out + (long)c*outStride;

  if (pos < d){
    const float4* s4p = (const float4*)src_c;
    float4* d4p = (float4*)op;
    #pragma unroll
    for (int it = 0; it < 8; ++it) d4p[tid + it*512] = s4p[tid + it*512];
    return;
  }
  const float* src_cd = ks_src(in, z0, pbend, c - d, init_mode);
  __shared__ ushort_t StH[16384], StL[16384];
  ks_gemm_body(PH, PL, src_c, src_cd, op, StH, StL);
}

// Parallel replay correction: inits[8s+i] = LS[8s+i-1] + h[s] @ A8^i,
// h[s] = inits[8s]. Grid (i-1, s). Plane source: i==1 -> A8H/A8L, else
// A8PH/A8PL slots 1..6 (A^16..A^56).
__global__ __launch_bounds__(512) void replay_corr(
    const ushort_t* __restrict__ A8H, const ushort_t* __restrict__ A8L,
    const ushort_t* __restrict__ A8PH, const ushort_t* __restrict__ A8PL,
    const float* __restrict__ pb, float* __restrict__ inits)
{
  int i = blockIdx.x + 1;     // 1..7
  int s = blockIdx.y;         // 0..15
  const ushort_t* PH = (i == 1) ? A8H : (A8PH + (long)(i-1)*65536);
  const ushort_t* PL = (i == 1) ? A8L : (A8PL + (long)(i-1)*65536);
  __shared__ ushort_t StH[16384], StL[16384];
  ks_gemm_body(PH, PL,
               pb + (long)(8*s + i - 1)*(Bb*Ll),
               inits + (long)(8*s)*(Bb*Ll),
               inits + (long)(8*s + i)*(Bb*Ll), StH, StL);
}

// ---------------------------------------------------------------------------
// Correction GEMMs: out[b, c*CC+j, :] += inits[c*64+b] @ A^(j+1).
// W staging async via global_load_lds (wave-contiguous layout).
// ---------------------------------------------------------------------------
__global__ __launch_bounds__(256) void gemm_corr(
    const float* __restrict__ inits, const ushort_t* __restrict__ AjH,
    const ushort_t* __restrict__ AjL, float* __restrict__ out)
{
  int jz = blockIdx.z;
  const ushort_t* Whp = AjH + (long)jz*65536;
  const ushort_t* Wlp = AjL + (long)jz*65536;
  __shared__ __align__(16) ushort_t Xh[4*128*8], Xl[4*128*8];
  __shared__ __align__(16) ushort_t Wh[4*128*8], Wl[4*128*8];

  int tid  = threadIdx.x;
  int wave = tid >> 6, lane = tid & 63;
  int wm = wave & 1, wn = wave >> 1;
  int quad = lane >> 4, l16 = lane & 15;
  int row0 = blockIdx.y * 128;
  int col0 = blockIdx.x * 128;

  f32x4 acc[4][4];
  #pragma unroll
  for (int mt = 0; mt < 4; ++mt)
    #pragma unroll
    for (int nt = 0; nt < 4; ++nt) acc[mt][nt] = (f32x4){0.f,0.f,0.f,0.f};

  for (int kt = 0; kt < 8; ++kt){
    #pragma unroll
    for (int it = 0; it < 2; ++it){
      int idx = tid + it*256;
      int q = idx >> 7, m = idx & 127;
      int n = idx & 127;
      long src = (long)(kt*4 + q)*256 + col0 + n;
      gld16(&((uint4*)Wh)[q*128 + n], &((const uint4*)Whp)[src]);
      gld16(&((uint4*)Wl)[q*128 + n], &((const uint4*)Wlp)[src]);
      const float* xp = &inits[(long)(row0 + m)*256 + kt*32 + q*8];
      float4 v0 = *(const float4*)xp;
      float4 v1 = *(const float4*)(xp + 4);
      float vv[8] = {v0.x,v0.y,v0.z,v0.w,v1.x,v1.y,v1.z,v1.w};
      ushort_t hs[8], ls[8];
      #pragma unroll
      for (int j = 0; j < 8; ++j){
        hs[j] = f2bf(vv[j]);
        ls[j] = f2bf(vv[j] - bf2f(hs[j]));
      }
      *(uint4*)&Xh[(q*128 + m)*8] = *(const uint4*)hs;
      *(uint4*)&Xl[(q*128 + m)*8] = *(const uint4*)ls;
    }
    __syncthreads();
    short8 ah[4], al[4], bh[4], bl[4];
    #pragma unroll
    for (int mt = 0; mt < 4; ++mt){
      int off = (quad*128 + wm*64 + mt*16 + l16)*8;
      ah[mt] = *(const short8*)&Xh[off];
      al[mt] = *(const short8*)&Xl[off];
    }
    #pragma unroll
    for (int nt = 0; nt < 4; ++nt){
      int off = (quad*128 + wn*64 + nt*16 + l16)*8;
      bh[nt] = *(const short8*)&Wh[off];
      bl[nt] = *(const short8*)&Wl[off];
    }
    #pragma unroll
    for (int mt = 0; mt < 4; ++mt)
      #pragma unroll
      for (int nt = 0; nt < 4; ++nt){
        acc[mt][nt] = __builtin_amdgcn_mfma_f32_16x16x32_bf16(ah[mt], bh[nt], acc[mt][nt], 0,0,0);
        acc[mt][nt] = __builtin_amdgcn_mfma_f32_16x16x32_bf16(ah[mt], bl[nt], acc[mt][nt], 0,0,0);
        acc[mt][nt] = __builtin_amdgcn_mfma_f32_16x16x32_bf16(al[mt], bh[nt], acc[mt][nt], 0,0,0);
      }
    __syncthreads();
  }

  #pragma unroll
  for (int mt = 0; mt < 4; ++mt){
    #pragma unroll
    for (int nt = 0; nt < 4; ++nt){
      int col = col0 + wn*64 + nt*16 + l16;
      #pragma unroll
      for (int reg = 0; reg < 4; ++reg){
        int row = row0 + wm*64 + mt*16 + quad*4 + reg;
        int b = row & 63, c = row >> 6;
        int t = c*CC + jz;
        long addr = ((long)b*Tt + t)*Ll + col;
        out[addr] += acc[mt][nt][reg];
      }
    }
  }
}

// ---------------------------------------------------------------------------
// Decoder split-bf16 MFMA GEMM, generalized wave grid:
//   WM x WN waves (TH = WM*WN*64 threads), per-wave tile (BM/WM)x(BN/WN).
// L1/L2: 128x128, 8 waves (2Mx4N) — half the staging per MFMA vs 64x128.
// L3:    64x128, 4 waves (2Mx2N) — unchanged from the verified config.
// Plane-staged operands use async global_load_lds width=16.
// ---------------------------------------------------------------------------
template<int BM, int BN, int WM, int WN, int TH, bool INS, bool OUTS>
__global__ __launch_bounds__(TH) void gemm_mfma(
    const float* __restrict__ X,
    const ushort_t* __restrict__ Xhp, const ushort_t* __restrict__ Xlp,
    const ushort_t* __restrict__ Whp, const ushort_t* __restrict__ Wlp,
    const float* __restrict__ bias, float* __restrict__ Y,
    ushort_t* __restrict__ Yh, ushort_t* __restrict__ Yl,
    int Mrows, int K, int N, int act)
{
  constexpr int BMh = BM/WM, BNq = BN/WN;
  constexpr int MT = BMh/16, NT = BNq/16;
  __shared__ __align__(16) ushort_t Xh[4*BM*8], Xl[4*BM*8];
  __shared__ __align__(16) ushort_t Wh[4*BN*8], Wl[4*BN*8];

  int tid  = threadIdx.x;
  int wave = tid >> 6, lane = tid & 63;
  int wm = wave % WM, wn = wave / WM;
  int quad = lane >> 4, l16 = lane & 15;
  long row0 = (long)blockIdx.y * BM;
  int col0 = blockIdx.x * BN;

  f32x4 acc[MT][NT];
  #pragma unroll
  for (int mt = 0; mt < MT; ++mt)
    #pragma unroll
    for (int nt = 0; nt < NT; ++nt) acc[mt][nt] = (f32x4){0.f,0.f,0.f,0.f};

  for (int kt = 0; kt < K; kt += 32){
    int ktile = kt >> 5;
    if constexpr (INS){
      #pragma unroll
      for (int it = 0; it < (BM*4)/TH; ++it){
        int idx = tid + it*TH;
        int q = idx / BM, m = idx % BM;
        long src = (long)(ktile*4 + q)*Mrows + row0 + m;
        gld16(&((uint4*)Xh)[q*BM + m], &((const uint4*)Xhp)[src]);
        gld16(&((uint4*)Xl)[q*BM + m], &((const uint4*)Xlp)[src]);
      }
    } else {
      #pragma unroll
      for (int it = 0; it < (BM*4)/TH; ++it){
        int idx = tid + it*TH;
        int q = idx / BM, m = idx % BM;
        const float* xp = &X[(row0 + m)*(long)K + kt + q*8];
        float4 v0 = *(const float4*)xp;
        float4 v1 = *(const float4*)(xp + 4);
        float vv[8] = {v0.x,v0.y,v0.z,v0.w,v1.x,v1.y,v1.z,v1.w};
        ushort_t hs[8], ls[8];
        #pragma unroll
        for (int j = 0; j < 8; ++j){
          hs[j] = f2bf(vv[j]);
          ls[j] = f2bf(vv[j] - bf2f(hs[j]));
        }
        *(uint4*)&Xh[(q*BM + m)*8] = *(const uint4*)hs;
        *(uint4*)&Xl[(q*BM + m)*8] = *(const uint4*)ls;
      }
    }
    #pragma unroll
    for (int it = 0; it < (BN*4)/TH; ++it){
      int idx = tid + it*TH;
      int q = idx / BN, n = idx % BN;
      long src = (long)(ktile*4 + q)*N + col0 + n;
      gld16(&((uint4*)Wh)[q*BN + n], &((const uint4*)Whp)[src]);
      gld16(&((uint4*)Wl)[q*BN + n], &((const uint4*)Wlp)[src]);
    }
    __syncthreads();

    short8 ah[MT], al[MT], bh[NT], bl[NT];
    #pragma unroll
    for (int mt = 0; mt < MT; ++mt){
      int off = (quad*BM + wm*BMh + mt*16 + l16)*8;
      ah[mt] = *(const short8*)&Xh[off];
      al[mt] = *(const short8*)&Xl[off];
    }
    #pragma unroll
    for (int nt = 0; nt < NT; ++nt){
      int off = (quad*BN + wn*BNq + nt*16 + l16)*8;
      bh[nt] = *(const short8*)&Wh[off];
      bl[nt] = *(const short8*)&Wl[off];
    }
    #pragma unroll
    for (int mt = 0; mt < MT; ++mt)
      #pragma unroll
      for (int nt = 0; nt < NT; ++nt){
        acc[mt][nt] = __builtin_amdgcn_mfma_f32_16x16x32_bf16(ah[mt], bh[nt], acc[mt][nt], 0, 0, 0);
        acc[mt][nt] = __builtin_amdgcn_mfma_f32_16x16x32_bf16(ah[mt], bl[nt], acc[mt][nt], 0, 0, 0);
        acc[mt][nt] = __builtin_amdgcn_mfma_f32_16x16x32_bf16(al[mt], bh[nt], acc[mt][nt], 0, 0, 0);
      }
    __syncthreads();
  }

  #pragma unroll
  for (int mt = 0; mt < MT; ++mt){
    long rowb = row0 + wm*BMh + mt*16 + quad*4;
    #pragma unroll
    for (int nt = 0; nt < NT; ++nt){
      int col = col0 + wn*BNq + nt*16 + l16;
      float bs = bias[col];
      #pragma unroll
      for (int reg = 0; reg < 4; ++reg){
        float y = acc[mt][nt][reg] + bs;
        if (act) y = LKY(y);
        long row = rowb + reg;
        if constexpr (OUTS){
          ushort_t h = f2bf(y);
          ushort_t l = f2bf(y - bf2f(h));
          long off = ((long)(col >> 3)*Mrows + row)*8 + (col & 7);
          Yh[off] = h; Yl[off] = l;
        } else {
          Y[row*(long)N + col] = y;
        }
      }
    }
  }
}

// ---------------------------------------------------------------------------
extern "C" void kernel_launch(void* const* d_in, const int* in_sizes, int n_in,
                              void* d_out, int out_size, void* d_ws, size_t ws_size,
                              hipStream_t stream) {
  const float* in0    = (const float*)d_in[0];
  const float* enc_w1 = (const float*)d_in[1];
  const float* enc_b1 = (const float*)d_in[2];
  const float* enc_w2 = (const float*)d_in[3];
  const float* enc_b2 = (const float*)d_in[4];
  const float* enc_w3 = (const float*)d_in[5];
  const float* enc_b3 = (const float*)d_in[6];
  const float* A_w    = (const float*)d_in[7];
  const float* B_w    = (const float*)d_in[8];
  const float* dec_w1 = (const float*)d_in[9];
  const float* dec_b1 = (const float*)d_in[10];
  const float* dec_w2 = (const float*)d_in[11];
  const float* dec_b2 = (const float*)d_in[12];
  const float* dec_w3 = (const float*)d_in[13];
  const float* dec_b3 = (const float*)d_in[14];
  float* out = (float*)d_out;

  // ---- workspace layout (float slots); total 9,437,184 fl = 37.75 MB ----
  float* ws    = (float*)d_ws;
  float* h1enc = ws;                      // 32768
  float* h2enc = ws + 32768;              // 32768
  float* s2    = ws + 65536;              // A^2
  float* s3    = ws + 131072;             // A^3
  float* s4    = ws + 196608;             // A^4
  float* s8    = ws + 262144;             // A^8
  float* s16   = ws + 327680;             // A^16
  float* s32   = ws + 393216;             // A^32
  float* s64   = ws + 458752;             // A^64
  ushort_t* Whp_d = (ushort_t*)(ws + 524288);   // decoder W planes
  ushort_t* Wlp_d = (ushort_t*)(ws + 786432);
  float* Rf    = ws + 1048576;            // R-pool: 8,388,608 fl
  // scan-phase layout of R:
  ushort_t* AjH = (ushort_t*)Rf;                // 8 planes x 65536 ush
  ushort_t* AjL = (ushort_t*)(Rf + 262144);
  ushort_t* BtH = (ushort_t*)(Rf + 524288);     // 8192 ush
  ushort_t* BtL = BtH + 8192;
  float* wend  = Rf + 532480;             // 2,097,152 (also KS-local ping buf)
  float* inits = Rf + 2629632;            // 2,097,152 (inits[0] = z0)
  float* g0    = Rf + 4726784;            // 262,144 (KS-global buf A)
  ushort_t* A64H = (ushort_t*)(Rf + 4988928);   // 65536 ush
  ushort_t* A64L = (ushort_t*)(Rf + 5021696);   // 65536 ush
  float* pb0   = Rf + 5054464;            // 2,097,152 (KS-local pong buf / LS)
  ushort_t* A8PH = (ushort_t*)(Rf + 7151616);   // slots 1..6 = A^16..A^56
  ushort_t* A8PL = (ushort_t*)(Rf + 7380992);
  ushort_t* A64PH = (ushort_t*)(Rf + 7610368);  // 3 planes (A128,A256,A512)
  ushort_t* A64PL = (ushort_t*)(Rf + 7708672);
  float* f24   = Rf + 7806976;            // fp32 A^24
  float* f128  = Rf + 7872512;            // fp32 A^128
  float* f256  = Rf + 7938048;            // fp32 A^256
  float* g1    = Rf + 8003584;            // 262,144 (KS-global buf B)
  // decoder-phase aliases of R (scan data dead by then):
  ushort_t* h1h = (ushort_t*)Rf;
  ushort_t* h1l = (ushort_t*)(Rf + 2097152);
  ushort_t* h2h = (ushort_t*)(Rf + 4194304);
  ushort_t* h2l = (ushort_t*)(Rf + 6291456);
  // A^8 hi/lo planes in fragment order: AjH/AjL plane 7.
  ushort_t* A8H = AjH + 7*65536;
  ushort_t* A8L = AjL + 7*65536;

  // Encoder (only t=0 feeds the scan) -> z0 into inits[0]  [split-K, 1024 blk]
  enc_dense<<<dim3(64,16), 256, 0, stream>>>(in0, Tt*Dd, enc_w1, enc_b1, h1enc, 256, 512, 1);
  enc_dense<<<dim3(64,16), 256, 0, stream>>>(h1enc, 512, enc_w2, enc_b2, h2enc, 512, 512, 1);
  enc_dense<<<dim3(64, 8), 256, 0, stream>>>(h2enc, 512, enc_w3, enc_b3, inits, 512, 256, 1);

  // A^1 plane + B planes
  prep_a1bw<<<288, 256, 0, stream>>>(A_w, B_w, AjH, AjL, BtH, BtL);

  // A-power chain, batched by dependency level (critical path = 9 launches)
  auto mj = [](const float* X, const float* Y, float* Cf, ushort_t* Ch, ushort_t* Cl){
    MMJob r; r.X = X; r.Y = Y; r.Cf = Cf; r.Ch = Ch; r.Cl = Cl; return r;
  };
  { MMJobs J = {};
    J.j[0] = mj(A_w, A_w, s2, AjH+1*65536, AjL+1*65536);                 // A^2
    matmul_gb<<<dim3(256,1), 256, 0, stream>>>(J); }
  { MMJobs J = {};
    J.j[0] = mj(s2, A_w, s3, AjH+2*65536, AjL+2*65536);                  // A^3
    J.j[1] = mj(s2, s2,  s4, AjH+3*65536, AjL+3*65536);                  // A^4
    matmul_gb<<<dim3(256,2), 256, 0, stream>>>(J); }
  { MMJobs J = {};
    J.j[0] = mj(s4, A_w, nullptr, AjH+4*65536, AjL+4*65536);             // A^5
    J.j[1] = mj(s4, s2,  nullptr, AjH+5*65536, AjL+5*65536);             // A^6
    J.j[2] = mj(s4, s3,  nullptr, AjH+6*65536, AjL+6*65536);             // A^7
    J.j[3] = mj(s4, s4,  s8, A8H, A8L);                                  // A^8
    matmul_gb<<<dim3(256,4), 256, 0, stream>>>(J); }
  { MMJobs J = {};
    J.j[0] = mj(s8, s8, s16, A8PH+1*65536, A8PL+1*65536);                // A^16
    matmul_gb<<<dim3(256,1), 256, 0, stream>>>(J); }
  { MMJobs J = {};
    J.j[0] = mj(s16, s8,  f24, A8PH+2*65536, A8PL+2*65536);              // A^24
    J.j[1] = mj(s16, s16, s32, A8PH+3*65536, A8PL+3*65536);              // A^32
    matmul_gb<<<dim3(256,2), 256, 0, stream>>>(J); }
  { MMJobs J = {};
    J.j[0] = mj(s32, s8,  nullptr, A8PH+4*65536, A8PL+4*65536);          // A^40
    J.j[1] = mj(s32, s16, nullptr, A8PH+5*65536, A8PL+5*65536);          // A^48
    J.j[2] = mj(s32, f24, nullptr, A8PH+6*65536, A8PL+6*65536);          // A^56
    J.j[3] = mj(s32, s32, s64, A64H, A64L);                              // A^64
    matmul_gb<<<dim3(256,4), 256, 0, stream>>>(J); }
  { MMJobs J = {};
    J.j[0] = mj(s64, s64, f128, A64PH+0*65536, A64PL+0*65536);           // A^128
    matmul_gb<<<dim3(256,1), 256, 0, stream>>>(J); }
  { MMJobs J = {};
    J.j[0] = mj(f128, f128, f256, A64PH+1*65536, A64PL+1*65536);         // A^256
    matmul_gb<<<dim3(256,1), 256, 0, stream>>>(J); }
  { MMJobs J = {};
    J.j[0] = mj(f256, f256, nullptr, A64PH+2*65536, A64PL+2*65536);      // A^512
    matmul_gb<<<dim3(256,1), 256, 0, stream>>>(J); }

  // Decoder weight planes (fused)
  prep_dec<<<2048, 256, 0, stream>>>(dec_w1, dec_w2, dec_w3, Whp_d, Wlp_d);

  // Pass 1: MFMA zero-init chunk scans (N-split: 256 blocks)
  scan_mfma<<<dim3(NCh, 2), 256, 0, stream>>>(in0, AjH, AjL, BtH, BtL, wend, out);

  // Pass 2a: KS-local — within-superchunk inclusive prefixes LS[c] over A^8.
  ks_round<<<128, 512, 0, stream>>>(A8H, A8L, wend, nullptr, nullptr, pb0, Bb*Ll, 1, 1, 0);
  ks_round<<<128, 512, 0, stream>>>(A8PH+1*65536, A8PL+1*65536, pb0, nullptr, nullptr, wend, Bb*Ll, 2, 1, 0);
  ks_round<<<128, 512, 0, stream>>>(A8PH+3*65536, A8PL+3*65536, wend, nullptr, nullptr, pb0, Bb*Ll, 4, 1, 0);
  // Pass 2b: KS-global — superchunk inits h[s] over A^64 (init: z0, LS ends).
  ks_round<<<16, 512, 0, stream>>>(A64H, A64L, nullptr, inits, pb0, g1, Bb*Ll, 1, 0, 1);
  ks_round<<<16, 512, 0, stream>>>(A64PH+0*65536, A64PL+0*65536, g1, nullptr, nullptr, g0, Bb*Ll, 2, 0, 0);
  ks_round<<<16, 512, 0, stream>>>(A64PH+1*65536, A64PL+1*65536, g0, nullptr, nullptr, g1, Bb*Ll, 4, 0, 0);
  ks_round<<<16, 512, 0, stream>>>(A64PH+2*65536, A64PL+2*65536, g1, nullptr, nullptr, inits, (long)SC*Bb*Ll, 8, 0, 0);
  // Pass 2c: parallel replay correction: inits[8s+i] = LS[8s+i-1] + h[s]@A8^i
  replay_corr<<<dim3(7, 16), 512, 0, stream>>>(A8H, A8L, A8PH, A8PL, pb0, inits);

  // Pass 3 (parallel corrections): out[b, c*8+j, :] += inits[c] @ A^(j+1)
  gemm_corr<<<dim3(2, 64, 8), 256, 0, stream>>>(inits, AjH, AjL, out);

  // Decoder: 3-layer MLP, split-bf16 MFMA, gld_lds staging.
  // L1/L2: 128x128 tiles, 8 waves (2Mx4N). L3: 64x128, 4 waves (unchanged).
  for (int rc = 0; rc < DEC_CHUNKS; ++rc){
    const float* zc = out + (long)rc*DEC_ROWS*Ll;
    float* oc       = out + (long)rc*DEC_ROWS*Ll;
    gemm_mfma<128,128,2,4,512,false,true><<<dim3(Ee/128, DEC_ROWS/128), 512, 0, stream>>>(
        zc, nullptr, nullptr, Whp_d, Wlp_d, dec_b1, nullptr, h1h, h1l, DEC_ROWS, Ll, Ee, 1);
    gemm_mfma<128,128,2,4,512,true,true><<<dim3(Ee/128, DEC_ROWS/128), 512, 0, stream>>>(
        nullptr, h1h, h1l, Whp_d + 131072, Wlp_d + 131072, dec_b2, nullptr, h2h, h2l, DEC_ROWS, Ee, Ee, 1);
    gemm_mfma<64,128,2,2,256,true,false><<<dim3(Ss/128, DEC_ROWS/64), 256, 0, stream>>>(
        nullptr, h2h, h2l, Whp_d + 393216, Wlp_d + 393216, dec_b3, oc, nullptr, nullptr, DEC_ROWS, Ee, Ss, 0);
  }
}

// Round 9
// 944.118 us; speedup vs baseline: 1.0775x; 1.0775x over previous
//
#include <hip/hip_runtime.h>

// Problem dims
constexpr int Bb  = 64;      // batch
constexpr int Tt  = 1024;    // time
constexpr int Dd  = 288;     // padded input feature dim
constexpr int Ss  = 256;     // STATE_DIM
constexpr int ALa = 16;      // ACT_LEN
constexpr int Ll  = 256;     // LATENT
constexpr int Ee  = 512;     // ENC
constexpr int CC  = 8;       // scan chunk length
constexpr int NCh = 128;     // number of chunks (CC*NCh == Tt)
constexpr int NSC = 16;      // superchunks for boundary recurrence
constexpr int SC  = 8;       // chunk-boundaries per superchunk
constexpr int DEC_CHUNKS = 8;
constexpr int DEC_ROWS = (Bb*Tt)/DEC_CHUNKS;  // 8192 rows per chunk

#define LKY(v) ((v) >= 0.f ? (v) : 0.01f*(v))

using f32x4  = __attribute__((ext_vector_type(4))) float;
using short8 = __attribute__((ext_vector_type(8))) short;
typedef unsigned short ushort_t;

__device__ __forceinline__ unsigned short f2bf(float f){
  unsigned int u = __float_as_uint(f);
  u = (u + 0x7fffu + ((u >> 16) & 1u)) >> 16;   // RNE
  return (unsigned short)u;
}
__device__ __forceinline__ float bf2f(unsigned short h){
  return __uint_as_float(((unsigned int)h) << 16);
}

// Async global->LDS 16B copy. LDS dest must be wave-uniform-base + lane*16
// (all call sites below satisfy this: per-wave q is constant, lane index is
// contiguous). Bytes land after the vmcnt(0) drain at __syncthreads().
__device__ __forceinline__ void gld16(void* lds, const void* g){
  __builtin_amdgcn_global_load_lds(
      (__attribute__((address_space(1))) void*)g,
      (__attribute__((address_space(3))) void*)lds, 16, 0, 0);
}

// ---------------------------------------------------------------------------
// Encoder dense layer, split-K: grid (row, N/32); 256 thr = 32 cols x 8 kslc.
// (1024 blocks of split-K beat 64 fat blocks by ~130 us.)
// ---------------------------------------------------------------------------
__global__ __launch_bounds__(256) void enc_dense(
    const float* __restrict__ xin, int xstride,
    const float* __restrict__ W, const float* __restrict__ bias,
    float* __restrict__ out, int K, int N, int act)
{
  int b = blockIdx.x, col0 = blockIdx.y * 32;
  int tid = threadIdx.x;
  int tx = tid & 31, tk = tid >> 5;
  __shared__ float x[512];
  __shared__ float part[8][33];
  for (int k = tid; k < K; k += 256) x[k] = xin[(long)b*xstride + k];
  __syncthreads();
  int j = col0 + tx;
  float p0=0.f,p1=0.f,p2=0.f,p3=0.f;
  int iters = K >> 3;
  #pragma unroll 2
  for (int i = 0; i < iters; i += 4){
    int k0 = tk + 8*i;
    p0 = fmaf(x[k0     ], W[(long)(k0     )*N + j], p0);
    p1 = fmaf(x[k0 +  8], W[(long)(k0 +  8)*N + j], p1);
    p2 = fmaf(x[k0 + 16], W[(long)(k0 + 16)*N + j], p2);
    p3 = fmaf(x[k0 + 24], W[(long)(k0 + 24)*N + j], p3);
  }
  part[tk][tx] = (p0+p1)+(p2+p3);
  __syncthreads();
  if (tid < 32){
    float s = part[0][tid];
    #pragma unroll
    for (int q = 1; q < 8; ++q) s += part[q][tid];
    s += bias[col0 + tid];
    out[b*N + col0 + tid] = act ? LKY(s) : s;
  }
}

// ---------------------------------------------------------------------------
// Batched 256x256 matmul C = X @ Y (up to 4 jobs per launch, blockIdx.y=job).
// Optional fp32 out + split planes ((k>>3)*256+n)*8+(k&7).
// ---------------------------------------------------------------------------
struct MMJob { const float* X; const float* Y; float* Cf; ushort_t* Ch; ushort_t* Cl; };
struct MMJobs { MMJob j[4]; };

__global__ __launch_bounds__(256) void matmul_gb(MMJobs jobs)
{
  MMJob jb = jobs.j[blockIdx.y];
  int i = blockIdx.x;
  int tid = threadIdx.x;
  int jg = tid & 63, tk = tid >> 6;
  __shared__ float row[256];
  __shared__ float4 part[4][64];
  if (tid < 256) row[tid] = jb.X[i*256 + tid];
  __syncthreads();
  int j4 = jg*4;
  float4 p0 = make_float4(0,0,0,0), p1 = make_float4(0,0,0,0);
  int kb = tk*64;
  #pragma unroll 4
  for (int k = kb; k < kb+64; k += 2){
    float x0 = row[k], x1 = row[k+1];
    float4 y0 = *(const float4*)&jb.Y[(k  )*256 + j4];
    float4 y1 = *(const float4*)&jb.Y[(k+1)*256 + j4];
    p0.x = fmaf(x0,y0.x,p0.x); p0.y = fmaf(x0,y0.y,p0.y);
    p0.z = fmaf(x0,y0.z,p0.z); p0.w = fmaf(x0,y0.w,p0.w);
    p1.x = fmaf(x1,y1.x,p1.x); p1.y = fmaf(x1,y1.y,p1.y);
    p1.z = fmaf(x1,y1.z,p1.z); p1.w = fmaf(x1,y1.w,p1.w);
  }
  p0.x+=p1.x; p0.y+=p1.y; p0.z+=p1.z; p0.w+=p1.w;
  part[tk][jg] = p0;
  __syncthreads();
  if (tid < 64){
    float4 s = part[0][tid];
    #pragma unroll
    for (int q = 1; q < 4; ++q){
      float4 v = part[q][tid];
      s.x+=v.x; s.y+=v.y; s.z+=v.z; s.w+=v.w;
    }
    int j = tid*4;
    if (jb.Cf) *(float4*)&jb.Cf[i*256 + j] = s;
    if (jb.Ch){
      float vv[4] = {s.x,s.y,s.z,s.w};
      #pragma unroll
      for (int e = 0; e < 4; ++e){
        ushort_t h = f2bf(vv[e]);
        int o = ((i>>3)*256 + j + e)*8 + (i&7);
        jb.Ch[o] = h; jb.Cl[o] = f2bf(vv[e] - bf2f(h));
      }
    }
  }
}

// ---------------------------------------------------------------------------
// Fused plane prep: A^1 plane (65536 elems) + B_w^T padded plane (8192 elems).
// ---------------------------------------------------------------------------
__global__ __launch_bounds__(256) void prep_a1bw(
    const float* __restrict__ A, const float* __restrict__ B,
    ushort_t* __restrict__ AH, ushort_t* __restrict__ AL,
    ushort_t* __restrict__ Bh, ushort_t* __restrict__ Bl)
{
  int o = blockIdx.x*256 + threadIdx.x;
  if (o < 65536){
    int j = o & 7, rest = o >> 3;
    int n = rest & 255, t8 = rest >> 8;
    int k = t8*8 + j;
    float v = A[k*256 + n];
    ushort_t h = f2bf(v);
    AH[o] = h; AL[o] = f2bf(v - bf2f(h));
  } else {
    int ob = o - 65536;                      // 0..8191
    int j = ob & 7, rest = ob >> 3;
    int n = rest & 255, kq = rest >> 8;
    int k = kq*8 + j;
    float v = (k < ALa) ? B[k*256 + n] : 0.f;
    ushort_t h = f2bf(v);
    Bh[ob] = h; Bl[ob] = f2bf(v - bf2f(h));
  }
}

// ---------------------------------------------------------------------------
// Fused decoder weight-plane prep (w1: 131072, w2: 262144, w3: 131072 elems).
// ---------------------------------------------------------------------------
__global__ __launch_bounds__(256) void prep_dec(
    const float* __restrict__ w1, const float* __restrict__ w2,
    const float* __restrict__ w3, ushort_t* __restrict__ Wh,
    ushort_t* __restrict__ Wl)
{
  long o = (long)blockIdx.x*256 + threadIdx.x;   // 0..524287
  const float* W; ushort_t* H; ushort_t* L; int N; long oo;
  if (o < 131072){ W = w1; H = Wh;          L = Wl;          N = 512; oo = o; }
  else if (o < 393216){ W = w2; H = Wh + 131072; L = Wl + 131072; N = 512; oo = o - 131072; }
  else { W = w3; H = Wh + 393216; L = Wl + 393216; N = 256; oo = o - 393216; }
  int j = (int)(oo & 7);
  long rest = oo >> 3;
  int n = (int)(rest % N);
  int t8 = (int)(rest / N);
  int k = t8*8 + j;
  float v = W[(long)k*N + n];
  ushort_t h = f2bf(v);
  H[oo] = h; L[oo] = f2bf(v - bf2f(h));
}

// ---------------------------------------------------------------------------
// MFMA chunk scan (zero-init pass), N-SPLIT + M-SPLIT:
// grid (chunk, nb); 512 thr = 8 waves; each wave owns 32 latent rows (mt<2)
// of 32 batch columns. 2 waves/SIMD for latency hiding (was 1).
// wend/zout layouts and numerics unchanged.
// ---------------------------------------------------------------------------
__device__ __forceinline__ void load_afrag2(
    const ushort_t* __restrict__ P, int kq, int m0, short8* dst)
{
  #pragma unroll
  for (int mt = 0; mt < 2; ++mt)
    dst[mt] = *(const short8*)&P[((long)kq*256 + m0 + mt*16)*8];
}

__global__ __launch_bounds__(512) void scan_mfma(
    const float* __restrict__ in0,
    const ushort_t* __restrict__ AtH, const ushort_t* __restrict__ AtL,
    const ushort_t* __restrict__ BtH, const ushort_t* __restrict__ BtL,
    float* __restrict__ wend, float* __restrict__ zout)
{
  int chunk = blockIdx.x;
  int n0 = blockIdx.y * 32;            // batch-column half
  int tid = threadIdx.x;
  int wave = tid >> 6, lane = tid & 63;
  int quad = lane >> 4, l16 = lane & 15;
  int mwave = wave * 32;               // 8 waves x 32 latent rows
  int m0 = mwave + l16;

  __shared__ ushort_t StH[8192];
  __shared__ ushort_t StL[8192];

  short8 Bfh[2], Bfl[2];
  #pragma unroll
  for (int mt = 0; mt < 2; ++mt){
    int off = ((quad)*256 + m0 + mt*16)*8;
    Bfh[mt] = *(const short8*)&BtH[off];
    Bfl[mt] = *(const short8*)&BtL[off];
  }

  f32x4 acc[2][2];
  #pragma unroll
  for (int mt = 0; mt < 2; ++mt)
    #pragma unroll
    for (int nt = 0; nt < 2; ++nt) acc[mt][nt] = (f32x4){0.f,0.f,0.f,0.f};

  const float* ubase[2];
  #pragma unroll
  for (int nt = 0; nt < 2; ++nt)
    ubase[nt] = in0 + (long)(n0 + nt*16 + l16)*(Tt*Dd) + (Ss + ALa) + quad*8;

  short8 Ahb[2][2], Alb[2][2];

  for (int tt = 0; tt < CC; ++tt){
    int t = chunk*CC + tt;
    float4 uq[2][2];
    #pragma unroll
    for (int nt = 0; nt < 2; ++nt){
      if (quad < 2){
        const float* up = ubase[nt] + (long)t*Dd;
        uq[nt][0] = *(const float4*)up;
        uq[nt][1] = *(const float4*)(up + 4);
      } else {
        uq[nt][0] = make_float4(0,0,0,0); uq[nt][1] = make_float4(0,0,0,0);
      }
    }

    if (tt > 0){
      load_afrag2(AtH, 0*4 + quad, m0, Ahb[0]);
      load_afrag2(AtL, 0*4 + quad, m0, Alb[0]);
      #pragma unroll
      for (int kt = 0; kt < 8; ++kt){
        int cur = kt & 1;
        if (kt < 7){
          load_afrag2(AtH, (kt+1)*4 + quad, m0, Ahb[cur^1]);
          load_afrag2(AtL, (kt+1)*4 + quad, m0, Alb[cur^1]);
        }
        short8 Sbh[2], Sbl[2];
        #pragma unroll
        for (int nt = 0; nt < 2; ++nt){
          int off = ((kt*4 + quad)*32 + nt*16 + l16)*8;
          Sbh[nt] = *(const short8*)&StH[off];
          Sbl[nt] = *(const short8*)&StL[off];
        }
        #pragma unroll
        for (int mt = 0; mt < 2; ++mt)
          #pragma unroll
          for (int nt = 0; nt < 2; ++nt){
            acc[mt][nt] = __builtin_amdgcn_mfma_f32_16x16x32_bf16(Ahb[cur][mt], Sbh[nt], acc[mt][nt], 0,0,0);
            acc[mt][nt] = __builtin_amdgcn_mfma_f32_16x16x32_bf16(Ahb[cur][mt], Sbl[nt], acc[mt][nt], 0,0,0);
            acc[mt][nt] = __builtin_amdgcn_mfma_f32_16x16x32_bf16(Alb[cur][mt], Sbh[nt], acc[mt][nt], 0,0,0);
          }
      }
    }

    short8 uh[2], ul[2];
    #pragma unroll
    for (int nt = 0; nt < 2; ++nt){
      float v[8] = {uq[nt][0].x,uq[nt][0].y,uq[nt][0].z,uq[nt][0].w,
                    uq[nt][1].x,uq[nt][1].y,uq[nt][1].z,uq[nt][1].w};
      ushort_t hs[8], ls[8];
      #pragma unroll
      for (int j = 0; j < 8; ++j){
        hs[j] = f2bf(v[j]);
        ls[j] = f2bf(v[j] - bf2f(hs[j]));
      }
      uh[nt] = *(const short8*)hs; ul[nt] = *(const short8*)ls;
    }
    #pragma unroll
    for (int mt = 0; mt < 2; ++mt)
      #pragma unroll
      for (int nt = 0; nt < 2; ++nt){
        acc[mt][nt] = __builtin_amdgcn_mfma_f32_16x16x32_bf16(Bfh[mt], uh[nt], acc[mt][nt], 0,0,0);
        acc[mt][nt] = __builtin_amdgcn_mfma_f32_16x16x32_bf16(Bfh[mt], ul[nt], acc[mt][nt], 0,0,0);
        acc[mt][nt] = __builtin_amdgcn_mfma_f32_16x16x32_bf16(Bfl[mt], uh[nt], acc[mt][nt], 0,0,0);
      }

    __syncthreads();

    #pragma unroll
    for (int mt = 0; mt < 2; ++mt){
      int mb = mwave + mt*16 + quad*4;
      #pragma unroll
      for (int nt = 0; nt < 2; ++nt){
        int n = nt*16 + l16;
        int gn = n0 + n;
        f32x4 v = acc[mt][nt];
        *(float4*)&zout[((long)gn*Tt + t)*Ll + mb] = make_float4(v[0],v[1],v[2],v[3]);
        if (tt == CC-1)
          *(float4*)&wend[((long)chunk*Bb + gn)*Ll + mb] = make_float4(v[0],v[1],v[2],v[3]);
        #pragma unroll
        for (int reg = 0; reg < 4; ++reg){
          int m = mb + reg;
          ushort_t h = f2bf(v[reg]);
          ushort_t l = f2bf(v[reg] - bf2f(h));
          int so = ((m>>3)*32 + n)*8 + (m&7);
          StH[so] = h; StL[so] = l;
        }
        acc[mt][nt] = (f32x4){0.f,0.f,0.f,0.f};
      }
    }
    __syncthreads();
  }
}

// ---------------------------------------------------------------------------
// pass2 (Kogge-Stone MFMA): boundary recurrence via parallel prefix-doubling.
// ---------------------------------------------------------------------------
__device__ __forceinline__ void frag_init_state512(
    const float* __restrict__ src, ushort_t* StH, ushort_t* StL, int tid)
{
  #pragma unroll
  for (int it = 0; it < 4; ++it){
    int idx = tid + it*512;        // 0..2047
    int m8 = idx >> 6, n = idx & 63;
    const float* p = src + (long)n*256 + m8*8;
    float4 v0 = *(const float4*)p;
    float4 v1 = *(const float4*)(p + 4);
    float vv[8] = {v0.x,v0.y,v0.z,v0.w,v1.x,v1.y,v1.z,v1.w};
    ushort_t hs[8], ls[8];
    #pragma unroll
    for (int j = 0; j < 8; ++j){
      hs[j] = f2bf(vv[j]);
      ls[j] = f2bf(vv[j] - bf2f(hs[j]));
    }
    *(uint4*)&StH[(m8*64 + n)*8] = *(const uint4*)hs;
    *(uint4*)&StL[(m8*64 + n)*8] = *(const uint4*)ls;
  }
}

__device__ __forceinline__ void p2_load_A(
    const ushort_t* __restrict__ PH, const ushort_t* __restrict__ PL,
    int wave, int lane, short8 Ah[2][8], short8 Al[2][8])
{
  int quad = lane >> 4, l16 = lane & 15;
  int m0 = wave*32 + l16;
  #pragma unroll
  for (int kt = 0; kt < 8; ++kt){
    int kq = kt*4 + quad;
    #pragma unroll
    for (int mt = 0; mt < 2; ++mt){
      Ah[mt][kt] = *(const short8*)&PH[((long)kq*256 + m0 + mt*16)*8];
      Al[mt][kt] = *(const short8*)&PL[((long)kq*256 + m0 + mt*16)*8];
    }
  }
}

// out = accsrc + bsrc @ P  (single barrier; no LDS writeback)
__device__ __forceinline__ void ks_gemm_body(
    const ushort_t* __restrict__ PH, const ushort_t* __restrict__ PL,
    const float* __restrict__ accsrc, const float* __restrict__ bsrc,
    float* __restrict__ outp, ushort_t* StH, ushort_t* StL)
{
  int tid = threadIdx.x;
  int wave = tid >> 6, lane = tid & 63;
  int quad = lane >> 4, l16 = lane & 15;
  int mwave = wave*32;

  short8 Ah[2][8], Al[2][8];
  p2_load_A(PH, PL, wave, lane, Ah, Al);
  frag_init_state512(bsrc, StH, StL, tid);

  f32x4 acc[2][4];
  #pragma unroll
  for (int mt = 0; mt < 2; ++mt){
    int mb = mwave + mt*16 + quad*4;
    #pragma unroll
    for (int nt = 0; nt < 4; ++nt){
      int n = nt*16 + l16;
      float4 v = *(const float4*)&accsrc[(long)n*256 + mb];
      acc[mt][nt] = (f32x4){v.x, v.y, v.z, v.w};
    }
  }
  __syncthreads();

  #pragma unroll
  for (int kt = 0; kt < 8; ++kt){
    #pragma unroll
    for (int nt = 0; nt < 4; ++nt){
      int off = ((kt*4 + quad)*64 + nt*16 + l16)*8;
      short8 Sbh = *(const short8*)&StH[off];
      short8 Sbl = *(const short8*)&StL[off];
      #pragma unroll
      for (int mt = 0; mt < 2; ++mt){
        acc[mt][nt] = __builtin_amdgcn_mfma_f32_16x16x32_bf16(Ah[mt][kt], Sbh, acc[mt][nt], 0,0,0);
        acc[mt][nt] = __builtin_amdgcn_mfma_f32_16x16x32_bf16(Ah[mt][kt], Sbl, acc[mt][nt], 0,0,0);
        acc[mt][nt] = __builtin_amdgcn_mfma_f32_16x16x32_bf16(Al[mt][kt], Sbh, acc[mt][nt], 0,0,0);
      }
    }
  }

  #pragma unroll
  for (int mt = 0; mt < 2; ++mt){
    int mb = mwave + mt*16 + quad*4;
    #pragma unroll
    for (int nt = 0; nt < 4; ++nt){
      int n = nt*16 + l16;
      f32x4 v = acc[mt][nt];
      *(float4*)&outp[(long)n*256 + mb] = make_float4(v[0],v[1],v[2],v[3]);
    }
  }
}

// Source resolver for KS-global round 1 (virtual init sequence):
//   x[0] = z0, x[c] = LS[8c-1] (superchunk-local full prefix end).
__device__ __forceinline__ const float* ks_src(
    const float* __restrict__ in, const float* __restrict__ z0,
    const float* __restrict__ pbend, int c, int init_mode)
{
  if (!init_mode) return in + (long)c*(Bb*Ll);
  return (c == 0) ? z0 : (pbend + (long)(8*c - 1)*(Bb*Ll));
}

// One Kogge-Stone round: out[c] = in[c] + in[c-d] @ P  (or copy if below d
// within its segment). local_seg=1: 8-chunk segments; else global sequence.
__global__ __launch_bounds__(512) void ks_round(
    const ushort_t* __restrict__ PH, const ushort_t* __restrict__ PL,
    const float* __restrict__ in, const float* __restrict__ z0,
    const float* __restrict__ pbend,
    float* __restrict__ out, long outStride, int d, int local_seg, int init_mode)
{
  int c = blockIdx.x;
  int tid = threadIdx.x;
  int pos = local_seg ? (c & 7) : c;
  const float* src_c = ks_src(in, z0, pbend, c, init_mode);
  float* op = out + (long)c*outStride;

  if (pos < d){
    const float4* s4p = (const float4*)src_c;
    float4* d4p = (float4*)op;
    #pragma unroll
    for (int it = 0; it < 8; ++it) d4p[tid + it*512] = s4p[tid + it*512];
    return;
  }
  const float* src_cd = ks_src(in, z0, pbend, c - d, init_mode);
  __shared__ ushort_t StH[16384], StL[16384];
  ks_gemm_body(PH, PL, src_c, src_cd, op, StH, StL);
}

// Parallel replay correction: inits[8s+i] = LS[8s+i-1] + h[s] @ A8^i,
// h[s] = inits[8s]. Grid (i-1, s). Plane source: i==1 -> A8H/A8L, else
// A8PH/A8PL slots 1..6 (A^16..A^56).
__global__ __launch_bounds__(512) void replay_corr(
    const ushort_t* __restrict__ A8H, const ushort_t* __restrict__ A8L,
    const ushort_t* __restrict__ A8PH, const ushort_t* __restrict__ A8PL,
    const float* __restrict__ pb, float* __restrict__ inits)
{
  int i = blockIdx.x + 1;     // 1..7
  int s = blockIdx.y;         // 0..15
  const ushort_t* PH = (i == 1) ? A8H : (A8PH + (long)(i-1)*65536);
  const ushort_t* PL = (i == 1) ? A8L : (A8PL + (long)(i-1)*65536);
  __shared__ ushort_t StH[16384], StL[16384];
  ks_gemm_body(PH, PL,
               pb + (long)(8*s + i - 1)*(Bb*Ll),
               inits + (long)(8*s)*(Bb*Ll),
               inits + (long)(8*s + i)*(Bb*Ll), StH, StL);
}

// ---------------------------------------------------------------------------
// Correction GEMMs: out[b, c*CC+j, :] += inits[c*64+b] @ A^(j+1).
// W staging async via global_load_lds (wave-contiguous layout).
// ---------------------------------------------------------------------------
__global__ __launch_bounds__(256) void gemm_corr(
    const float* __restrict__ inits, const ushort_t* __restrict__ AjH,
    const ushort_t* __restrict__ AjL, float* __restrict__ out)
{
  int jz = blockIdx.z;
  const ushort_t* Whp = AjH + (long)jz*65536;
  const ushort_t* Wlp = AjL + (long)jz*65536;
  __shared__ __align__(16) ushort_t Xh[4*128*8], Xl[4*128*8];
  __shared__ __align__(16) ushort_t Wh[4*128*8], Wl[4*128*8];

  int tid  = threadIdx.x;
  int wave = tid >> 6, lane = tid & 63;
  int wm = wave & 1, wn = wave >> 1;
  int quad = lane >> 4, l16 = lane & 15;
  int row0 = blockIdx.y * 128;
  int col0 = blockIdx.x * 128;

  f32x4 acc[4][4];
  #pragma unroll
  for (int mt = 0; mt < 4; ++mt)
    #pragma unroll
    for (int nt = 0; nt < 4; ++nt) acc[mt][nt] = (f32x4){0.f,0.f,0.f,0.f};

  for (int kt = 0; kt < 8; ++kt){
    #pragma unroll
    for (int it = 0; it < 2; ++it){
      int idx = tid + it*256;
      int q = idx >> 7, m = idx & 127;
      int n = idx & 127;
      long src = (long)(kt*4 + q)*256 + col0 + n;
      gld16(&((uint4*)Wh)[q*128 + n], &((const uint4*)Whp)[src]);
      gld16(&((uint4*)Wl)[q*128 + n], &((const uint4*)Wlp)[src]);
      const float* xp = &inits[(long)(row0 + m)*256 + kt*32 + q*8];
      float4 v0 = *(const float4*)xp;
      float4 v1 = *(const float4*)(xp + 4);
      float vv[8] = {v0.x,v0.y,v0.z,v0.w,v1.x,v1.y,v1.z,v1.w};
      ushort_t hs[8], ls[8];
      #pragma unroll
      for (int j = 0; j < 8; ++j){
        hs[j] = f2bf(vv[j]);
        ls[j] = f2bf(vv[j] - bf2f(hs[j]));
      }
      *(uint4*)&Xh[(q*128 + m)*8] = *(const uint4*)hs;
      *(uint4*)&Xl[(q*128 + m)*8] = *(const uint4*)ls;
    }
    __syncthreads();
    short8 ah[4], al[4], bh[4], bl[4];
    #pragma unroll
    for (int mt = 0; mt < 4; ++mt){
      int off = (quad*128 + wm*64 + mt*16 + l16)*8;
      ah[mt] = *(const short8*)&Xh[off];
      al[mt] = *(const short8*)&Xl[off];
    }
    #pragma unroll
    for (int nt = 0; nt < 4; ++nt){
      int off = (quad*128 + wn*64 + nt*16 + l16)*8;
      bh[nt] = *(const short8*)&Wh[off];
      bl[nt] = *(const short8*)&Wl[off];
    }
    #pragma unroll
    for (int mt = 0; mt < 4; ++mt)
      #pragma unroll
      for (int nt = 0; nt < 4; ++nt){
        acc[mt][nt] = __builtin_amdgcn_mfma_f32_16x16x32_bf16(ah[mt], bh[nt], acc[mt][nt], 0,0,0);
        acc[mt][nt] = __builtin_amdgcn_mfma_f32_16x16x32_bf16(ah[mt], bl[nt], acc[mt][nt], 0,0,0);
        acc[mt][nt] = __builtin_amdgcn_mfma_f32_16x16x32_bf16(al[mt], bh[nt], acc[mt][nt], 0,0,0);
      }
    __syncthreads();
  }

  #pragma unroll
  for (int mt = 0; mt < 4; ++mt){
    #pragma unroll
    for (int nt = 0; nt < 4; ++nt){
      int col = col0 + wn*64 + nt*16 + l16;
      #pragma unroll
      for (int reg = 0; reg < 4; ++reg){
        int row = row0 + wm*64 + mt*16 + quad*4 + reg;
        int b = row & 63, c = row >> 6;
        int t = c*CC + jz;
        long addr = ((long)b*Tt + t)*Ll + col;
        out[addr] += acc[mt][nt][reg];
      }
    }
  }
}

// ---------------------------------------------------------------------------
// Decoder split-bf16 MFMA GEMM, generalized wave grid:
//   WM x WN waves (TH = WM*WN*64 threads), per-wave tile (BM/WM)x(BN/WN).
// All layers at 64x128, 4 waves (2Mx2N), 2 blocks/CU — r7-verified config.
// Plane-staged operands use async global_load_lds width=16.
// ---------------------------------------------------------------------------
template<int BM, int BN, int WM, int WN, int TH, bool INS, bool OUTS>
__global__ __launch_bounds__(TH) void gemm_mfma(
    const float* __restrict__ X,
    const ushort_t* __restrict__ Xhp, const ushort_t* __restrict__ Xlp,
    const ushort_t* __restrict__ Whp, const ushort_t* __restrict__ Wlp,
    const float* __restrict__ bias, float* __restrict__ Y,
    ushort_t* __restrict__ Yh, ushort_t* __restrict__ Yl,
    int Mrows, int K, int N, int act)
{
  constexpr int BMh = BM/WM, BNq = BN/WN;
  constexpr int MT = BMh/16, NT = BNq/16;
  __shared__ __align__(16) ushort_t Xh[4*BM*8], Xl[4*BM*8];
  __shared__ __align__(16) ushort_t Wh[4*BN*8], Wl[4*BN*8];

  int tid  = threadIdx.x;
  int wave = tid >> 6, lane = tid & 63;
  int wm = wave % WM, wn = wave / WM;
  int quad = lane >> 4, l16 = lane & 15;
  long row0 = (long)blockIdx.y * BM;
  int col0 = blockIdx.x * BN;

  f32x4 acc[MT][NT];
  #pragma unroll
  for (int mt = 0; mt < MT; ++mt)
    #pragma unroll
    for (int nt = 0; nt < NT; ++nt) acc[mt][nt] = (f32x4){0.f,0.f,0.f,0.f};

  for (int kt = 0; kt < K; kt += 32){
    int ktile = kt >> 5;
    if constexpr (INS){
      #pragma unroll
      for (int it = 0; it < (BM*4)/TH; ++it){
        int idx = tid + it*TH;
        int q = idx / BM, m = idx % BM;
        long src = (long)(ktile*4 + q)*Mrows + row0 + m;
        gld16(&((uint4*)Xh)[q*BM + m], &((const uint4*)Xhp)[src]);
        gld16(&((uint4*)Xl)[q*BM + m], &((const uint4*)Xlp)[src]);
      }
    } else {
      #pragma unroll
      for (int it = 0; it < (BM*4)/TH; ++it){
        int idx = tid + it*TH;
        int q = idx / BM, m = idx % BM;
        const float* xp = &X[(row0 + m)*(long)K + kt + q*8];
        float4 v0 = *(const float4*)xp;
        float4 v1 = *(const float4*)(xp + 4);
        float vv[8] = {v0.x,v0.y,v0.z,v0.w,v1.x,v1.y,v1.z,v1.w};
        ushort_t hs[8], ls[8];
        #pragma unroll
        for (int j = 0; j < 8; ++j){
          hs[j] = f2bf(vv[j]);
          ls[j] = f2bf(vv[j] - bf2f(hs[j]));
        }
        *(uint4*)&Xh[(q*BM + m)*8] = *(const uint4*)hs;
        *(uint4*)&Xl[(q*BM + m)*8] = *(const uint4*)ls;
      }
    }
    #pragma unroll
    for (int it = 0; it < (BN*4)/TH; ++it){
      int idx = tid + it*TH;
      int q = idx / BN, n = idx % BN;
      long src = (long)(ktile*4 + q)*N + col0 + n;
      gld16(&((uint4*)Wh)[q*BN + n], &((const uint4*)Whp)[src]);
      gld16(&((uint4*)Wl)[q*BN + n], &((const uint4*)Wlp)[src]);
    }
    __syncthreads();

    short8 ah[MT], al[MT], bh[NT], bl[NT];
    #pragma unroll
    for (int mt = 0; mt < MT; ++mt){
      int off = (quad*BM + wm*BMh + mt*16 + l16)*8;
      ah[mt] = *(const short8*)&Xh[off];
      al[mt] = *(const short8*)&Xl[off];
    }
    #pragma unroll
    for (int nt = 0; nt < NT; ++nt){
      int off = (quad*BN + wn*BNq + nt*16 + l16)*8;
      bh[nt] = *(const short8*)&Wh[off];
      bl[nt] = *(const short8*)&Wl[off];
    }
    #pragma unroll
    for (int mt = 0; mt < MT; ++mt)
      #pragma unroll
      for (int nt = 0; nt < NT; ++nt){
        acc[mt][nt] = __builtin_amdgcn_mfma_f32_16x16x32_bf16(ah[mt], bh[nt], acc[mt][nt], 0, 0, 0);
        acc[mt][nt] = __builtin_amdgcn_mfma_f32_16x16x32_bf16(ah[mt], bl[nt], acc[mt][nt], 0, 0, 0);
        acc[mt][nt] = __builtin_amdgcn_mfma_f32_16x16x32_bf16(al[mt], bh[nt], acc[mt][nt], 0, 0, 0);
      }
    __syncthreads();
  }

  #pragma unroll
  for (int mt = 0; mt < MT; ++mt){
    long rowb = row0 + wm*BMh + mt*16 + quad*4;
    #pragma unroll
    for (int nt = 0; nt < NT; ++nt){
      int col = col0 + wn*BNq + nt*16 + l16;
      float bs = bias[col];
      #pragma unroll
      for (int reg = 0; reg < 4; ++reg){
        float y = acc[mt][nt][reg] + bs;
        if (act) y = LKY(y);
        long row = rowb + reg;
        if constexpr (OUTS){
          ushort_t h = f2bf(y);
          ushort_t l = f2bf(y - bf2f(h));
          long off = ((long)(col >> 3)*Mrows + row)*8 + (col & 7);
          Yh[off] = h; Yl[off] = l;
        } else {
          Y[row*(long)N + col] = y;
        }
      }
    }
  }
}

// ---------------------------------------------------------------------------
extern "C" void kernel_launch(void* const* d_in, const int* in_sizes, int n_in,
                              void* d_out, int out_size, void* d_ws, size_t ws_size,
                              hipStream_t stream) {
  const float* in0    = (const float*)d_in[0];
  const float* enc_w1 = (const float*)d_in[1];
  const float* enc_b1 = (const float*)d_in[2];
  const float* enc_w2 = (const float*)d_in[3];
  const float* enc_b2 = (const float*)d_in[4];
  const float* enc_w3 = (const float*)d_in[5];
  const float* enc_b3 = (const float*)d_in[6];
  const float* A_w    = (const float*)d_in[7];
  const float* B_w    = (const float*)d_in[8];
  const float* dec_w1 = (const float*)d_in[9];
  const float* dec_b1 = (const float*)d_in[10];
  const float* dec_w2 = (const float*)d_in[11];
  const float* dec_b2 = (const float*)d_in[12];
  const float* dec_w3 = (const float*)d_in[13];
  const float* dec_b3 = (const float*)d_in[14];
  float* out = (float*)d_out;

  // ---- workspace layout (float slots); total 9,437,184 fl = 37.75 MB ----
  float* ws    = (float*)d_ws;
  float* h1enc = ws;                      // 32768
  float* h2enc = ws + 32768;              // 32768
  float* s2    = ws + 65536;              // A^2
  float* s3    = ws + 131072;             // A^3
  float* s4    = ws + 196608;             // A^4
  float* s8    = ws + 262144;             // A^8
  float* s16   = ws + 327680;             // A^16
  float* s32   = ws + 393216;             // A^32
  float* s64   = ws + 458752;             // A^64
  ushort_t* Whp_d = (ushort_t*)(ws + 524288);   // decoder W planes
  ushort_t* Wlp_d = (ushort_t*)(ws + 786432);
  float* Rf    = ws + 1048576;            // R-pool: 8,388,608 fl
  // scan-phase layout of R:
  ushort_t* AjH = (ushort_t*)Rf;                // 8 planes x 65536 ush
  ushort_t* AjL = (ushort_t*)(Rf + 262144);
  ushort_t* BtH = (ushort_t*)(Rf + 524288);     // 8192 ush
  ushort_t* BtL = BtH + 8192;
  float* wend  = Rf + 532480;             // 2,097,152 (also KS-local ping buf)
  float* inits = Rf + 2629632;            // 2,097,152 (inits[0] = z0)
  float* g0    = Rf + 4726784;            // 262,144 (KS-global buf A)
  ushort_t* A64H = (ushort_t*)(Rf + 4988928);   // 65536 ush
  ushort_t* A64L = (ushort_t*)(Rf + 5021696);   // 65536 ush
  float* pb0   = Rf + 5054464;            // 2,097,152 (KS-local pong buf / LS)
  ushort_t* A8PH = (ushort_t*)(Rf + 7151616);   // slots 1..6 = A^16..A^56
  ushort_t* A8PL = (ushort_t*)(Rf + 7380992);
  ushort_t* A64PH = (ushort_t*)(Rf + 7610368);  // 3 planes (A128,A256,A512)
  ushort_t* A64PL = (ushort_t*)(Rf + 7708672);
  float* f24   = Rf + 7806976;            // fp32 A^24
  float* f128  = Rf + 7872512;            // fp32 A^128
  float* f256  = Rf + 7938048;            // fp32 A^256
  float* g1    = Rf + 8003584;            // 262,144 (KS-global buf B)
  // decoder-phase aliases of R (scan data dead by then):
  ushort_t* h1h = (ushort_t*)Rf;
  ushort_t* h1l = (ushort_t*)(Rf + 2097152);
  ushort_t* h2h = (ushort_t*)(Rf + 4194304);
  ushort_t* h2l = (ushort_t*)(Rf + 6291456);
  // A^8 hi/lo planes in fragment order: AjH/AjL plane 7.
  ushort_t* A8H = AjH + 7*65536;
  ushort_t* A8L = AjL + 7*65536;

  // Encoder (only t=0 feeds the scan) -> z0 into inits[0]  [split-K, 1024 blk]
  enc_dense<<<dim3(64,16), 256, 0, stream>>>(in0, Tt*Dd, enc_w1, enc_b1, h1enc, 256, 512, 1);
  enc_dense<<<dim3(64,16), 256, 0, stream>>>(h1enc, 512, enc_w2, enc_b2, h2enc, 512, 512, 1);
  enc_dense<<<dim3(64, 8), 256, 0, stream>>>(h2enc, 512, enc_w3, enc_b3, inits, 512, 256, 1);

  // A^1 plane + B planes
  prep_a1bw<<<288, 256, 0, stream>>>(A_w, B_w, AjH, AjL, BtH, BtL);

  // A-power chain, batched by dependency level (critical path = 9 launches)
  auto mj = [](const float* X, const float* Y, float* Cf, ushort_t* Ch, ushort_t* Cl){
    MMJob r; r.X = X; r.Y = Y; r.Cf = Cf; r.Ch = Ch; r.Cl = Cl; return r;
  };
  { MMJobs J = {};
    J.j[0] = mj(A_w, A_w, s2, AjH+1*65536, AjL+1*65536);                 // A^2
    matmul_gb<<<dim3(256,1), 256, 0, stream>>>(J); }
  { MMJobs J = {};
    J.j[0] = mj(s2, A_w, s3, AjH+2*65536, AjL+2*65536);                  // A^3
    J.j[1] = mj(s2, s2,  s4, AjH+3*65536, AjL+3*65536);                  // A^4
    matmul_gb<<<dim3(256,2), 256, 0, stream>>>(J); }
  { MMJobs J = {};
    J.j[0] = mj(s4, A_w, nullptr, AjH+4*65536, AjL+4*65536);             // A^5
    J.j[1] = mj(s4, s2,  nullptr, AjH+5*65536, AjL+5*65536);             // A^6
    J.j[2] = mj(s4, s3,  nullptr, AjH+6*65536, AjL+6*65536);             // A^7
    J.j[3] = mj(s4, s4,  s8, A8H, A8L);                                  // A^8
    matmul_gb<<<dim3(256,4), 256, 0, stream>>>(J); }
  { MMJobs J = {};
    J.j[0] = mj(s8, s8, s16, A8PH+1*65536, A8PL+1*65536);                // A^16
    matmul_gb<<<dim3(256,1), 256, 0, stream>>>(J); }
  { MMJobs J = {};
    J.j[0] = mj(s16, s8,  f24, A8PH+2*65536, A8PL+2*65536);              // A^24
    J.j[1] = mj(s16, s16, s32, A8PH+3*65536, A8PL+3*65536);              // A^32
    matmul_gb<<<dim3(256,2), 256, 0, stream>>>(J); }
  { MMJobs J = {};
    J.j[0] = mj(s32, s8,  nullptr, A8PH+4*65536, A8PL+4*65536);          // A^40
    J.j[1] = mj(s32, s16, nullptr, A8PH+5*65536, A8PL+5*65536);          // A^48
    J.j[2] = mj(s32, f24, nullptr, A8PH+6*65536, A8PL+6*65536);          // A^56
    J.j[3] = mj(s32, s32, s64, A64H, A64L);                              // A^64
    matmul_gb<<<dim3(256,4), 256, 0, stream>>>(J); }
  { MMJobs J = {};
    J.j[0] = mj(s64, s64, f128, A64PH+0*65536, A64PL+0*65536);           // A^128
    matmul_gb<<<dim3(256,1), 256, 0, stream>>>(J); }
  { MMJobs J = {};
    J.j[0] = mj(f128, f128, f256, A64PH+1*65536, A64PL+1*65536);         // A^256
    matmul_gb<<<dim3(256,1), 256, 0, stream>>>(J); }
  { MMJobs J = {};
    J.j[0] = mj(f256, f256, nullptr, A64PH+2*65536, A64PL+2*65536);      // A^512
    matmul_gb<<<dim3(256,1), 256, 0, stream>>>(J); }

  // Decoder weight planes (fused)
  prep_dec<<<2048, 256, 0, stream>>>(dec_w1, dec_w2, dec_w3, Whp_d, Wlp_d);

  // Pass 1: MFMA zero-init chunk scans (N-split x M-split: 256 blocks, 8 waves)
  scan_mfma<<<dim3(NCh, 2), 512, 0, stream>>>(in0, AjH, AjL, BtH, BtL, wend, out);

  // Pass 2a: KS-local — within-superchunk inclusive prefixes LS[c] over A^8.
  ks_round<<<128, 512, 0, stream>>>(A8H, A8L, wend, nullptr, nullptr, pb0, Bb*Ll, 1, 1, 0);
  ks_round<<<128, 512, 0, stream>>>(A8PH+1*65536, A8PL+1*65536, pb0, nullptr, nullptr, wend, Bb*Ll, 2, 1, 0);
  ks_round<<<128, 512, 0, stream>>>(A8PH+3*65536, A8PL+3*65536, wend, nullptr, nullptr, pb0, Bb*Ll, 4, 1, 0);
  // Pass 2b: KS-global — superchunk inits h[s] over A^64 (init: z0, LS ends).
  ks_round<<<16, 512, 0, stream>>>(A64H, A64L, nullptr, inits, pb0, g1, Bb*Ll, 1, 0, 1);
  ks_round<<<16, 512, 0, stream>>>(A64PH+0*65536, A64PL+0*65536, g1, nullptr, nullptr, g0, Bb*Ll, 2, 0, 0);
  ks_round<<<16, 512, 0, stream>>>(A64PH+1*65536, A64PL+1*65536, g0, nullptr, nullptr, g1, Bb*Ll, 4, 0, 0);
  ks_round<<<16, 512, 0, stream>>>(A64PH+2*65536, A64PL+2*65536, g1, nullptr, nullptr, inits, (long)SC*Bb*Ll, 8, 0, 0);
  // Pass 2c: parallel replay correction: inits[8s+i] = LS[8s+i-1] + h[s]@A8^i
  replay_corr<<<dim3(7, 16), 512, 0, stream>>>(A8H, A8L, A8PH, A8PL, pb0, inits);

  // Pass 3 (parallel corrections): out[b, c*8+j, :] += inits[c] @ A^(j+1)
  gemm_corr<<<dim3(2, 64, 8), 256, 0, stream>>>(inits, AjH, AjL, out);

  // Decoder: 3-layer MLP, split-bf16 MFMA, 64x128 tiles (2 blocks/CU),
  // async global_load_lds staging — r7-verified config.
  for (int rc = 0; rc < DEC_CHUNKS; ++rc){
    const float* zc = out + (long)rc*DEC_ROWS*Ll;
    float* oc       = out + (long)rc*DEC_ROWS*Ll;
    gemm_mfma<64,128,2,2,256,false,true><<<dim3(Ee/128, DEC_ROWS/64), 256, 0, stream>>>(
        zc, nullptr, nullptr, Whp_d, Wlp_d, dec_b1, nullptr, h1h, h1l, DEC_ROWS, Ll, Ee, 1);
    gemm_mfma<64,128,2,2,256,true,true><<<dim3(Ee/128, DEC_ROWS/64), 256, 0, stream>>>(
        nullptr, h1h, h1l, Whp_d + 131072, Wlp_d + 131072, dec_b2, nullptr, h2h, h2l, DEC_ROWS, Ee, Ee, 1);
    gemm_mfma<64,128,2,2,256,true,false><<<dim3(Ss/128, DEC_ROWS/64), 256, 0, stream>>>(
        nullptr, h2h, h2l, Whp_d + 393216, Wlp_d + 393216, dec_b3, oc, nullptr, nullptr, DEC_ROWS, Ee, Ss, 0);
  }
}